// Round 2
// baseline (5700.172 us; speedup 1.0000x reference)
//
#include <hip/hip_runtime.h>
#include <hip/hip_bf16.h>

#define NVT 63    // ceil(32000/512) vocab tiles

__global__ void zero_kernel(float* p, int n){
  int i = blockIdx.x*blockDim.x + threadIdx.x;
  if (i < n) p[i] = 0.f;
}

// x_proj = gather(embedding, tok) @ W_ih + b : [2048,1024]@[1024,4096]
// grid (8,64), block 256. BM=32, BN=512 (2 cols/thread), BK=128.
__global__ __launch_bounds__(256,2) void xproj_kernel(
    const int* __restrict__ tok, const float* __restrict__ emb,
    const float* __restrict__ Wih, const float* __restrict__ bias,
    float* __restrict__ xproj)
{
  const int rt = blockIdx.y, ct = blockIdx.x;
  const int rowbase = rt*32;
  const int tid = threadIdx.x;
  const int col0 = ct*512 + tid, col1 = col0 + 256;
  __shared__ float A[32][128];
  __shared__ int rtok[32];
  if (tid < 32) rtok[tid] = tok[rowbase + tid];
  float acc0[32], acc1[32];
#pragma unroll
  for (int r=0;r<32;++r){acc0[r]=0.f;acc1[r]=0.f;}
  for (int kb=0; kb<1024; kb+=128){
    __syncthreads();
#pragma unroll
    for (int i=0;i<16;++i){
      int idx = i*256 + tid;
      int r = idx >> 7, c2 = idx & 127;
      A[r][c2] = emb[rtok[r]*1024 + kb + c2];
    }
    __syncthreads();
#pragma unroll 2
    for (int kk=0; kk<128; kk+=4){
      float wa[4], wb[4];
#pragma unroll
      for (int j=0;j<4;++j){
        wa[j] = Wih[(kb+kk+j)*4096 + col0];
        wb[j] = Wih[(kb+kk+j)*4096 + col1];
      }
#pragma unroll
      for (int r=0;r<32;++r){
        const float4 a = *(const float4*)&A[r][kk];
        acc0[r] += a.x*wa[0] + a.y*wa[1] + a.z*wa[2] + a.w*wa[3];
        acc1[r] += a.x*wb[0] + a.y*wb[1] + a.z*wb[2] + a.w*wb[3];
      }
    }
  }
  const float b0 = bias[col0], b1 = bias[col1];
#pragma unroll
  for (int r=0;r<32;++r){
    xproj[(rowbase+r)*4096 + col0] = acc0[r] + b0;
    xproj[(rowbase+r)*4096 + col1] = acc1[r] + b1;
  }
}

// One LSTM step: gates = xg_t + hprev @ W_hh, then pointwise.
// 256 blocks x 256 threads. Block owns 4 h-cols (16 gate cols, 64KB LDS, transposed,
// float4 XOR-swizzled). Threads: hc=t&3, bgrp=(t>>2)&7 (4 batches each), ks=t>>5 (8-way K split).
__global__ __launch_bounds__(256,2) void lstm_step(
    const float* __restrict__ xg_t, const float* __restrict__ Whh,
    const float* __restrict__ hprev, float* __restrict__ hnew,
    float* __restrict__ c, float* __restrict__ hs_t)
{
  const int cbase = blockIdx.x * 4;
  const int tid = threadIdx.x;
  __shared__ float4 W4[16*256];   // [row=q*4+j][k4], 64KB
  for (int idx = tid; idx < 4096; idx += 256){
    int k = idx >> 2, q = idx & 3;
    const float4 w = *(const float4*)&Whh[k*4096 + q*1024 + cbase];
    int k4 = k >> 2, kr = k & 3;
    { int row = q*4+0; ((float*)&W4[row*256 + (k4 ^ (row&3))])[kr] = w.x; }
    { int row = q*4+1; ((float*)&W4[row*256 + (k4 ^ (row&3))])[kr] = w.y; }
    { int row = q*4+2; ((float*)&W4[row*256 + (k4 ^ (row&3))])[kr] = w.z; }
    { int row = q*4+3; ((float*)&W4[row*256 + (k4 ^ (row&3))])[kr] = w.w; }
  }
  __syncthreads();
  const int hc = tid & 3, bgrp = (tid >> 2) & 7, ks = tid >> 5;
  const float4* hp4 = (const float4*)hprev;
  float acc[4][4]; // [nb][gate]
#pragma unroll
  for (int nb=0;nb<4;++nb)
#pragma unroll
    for (int q=0;q<4;++q) acc[nb][q]=0.f;
  for (int i=0;i<32;++i){
    const int k4 = ks*32 + i;
    float4 h4[4];
#pragma unroll
    for (int nb=0;nb<4;++nb) h4[nb] = hp4[(bgrp*4+nb)*256 + k4];
#pragma unroll
    for (int q=0;q<4;++q){
      const int row = q*4 + hc;
      const float4 w = W4[row*256 + (k4 ^ hc)];
#pragma unroll
      for (int nb=0;nb<4;++nb)
        acc[nb][q] += h4[nb].x*w.x + h4[nb].y*w.y + h4[nb].z*w.z + h4[nb].w*w.w;
    }
  }
  __syncthreads();
  float* P = (float*)W4;  // reuse LDS for 8-way ksplit reduce (16KB)
#pragma unroll
  for (int nb=0;nb<4;++nb)
#pragma unroll
    for (int q=0;q<4;++q) P[tid*16 + nb*4 + q] = acc[nb][q];
  __syncthreads();
  if (tid < 32){
#pragma unroll
    for (int nb=0;nb<4;++nb){
      const int b = bgrp*4 + nb;
      float s[4];
#pragma unroll
      for (int q=0;q<4;++q){
        float v = 0.f;
#pragma unroll
        for (int kss=0; kss<8; ++kss) v += P[(kss*32 + tid)*16 + nb*4 + q];
        s[q] = v;
      }
      const int col = cbase + hc;
      const float xi = xg_t[b*4096 + col];
      const float xf = xg_t[b*4096 + 1024 + col];
      const float xgv= xg_t[b*4096 + 2048 + col];
      const float xo = xg_t[b*4096 + 3072 + col];
      const float iv = 1.f/(1.f+__expf(-(xi + s[0])));
      const float fv = 1.f/(1.f+__expf(-(xf + s[1])));
      const float gv = tanhf(xgv + s[2]);
      const float ov = 1.f/(1.f+__expf(-(xo + s[3])));
      const float cn = fv*c[b*1024 + col] + iv*gv;
      const float hv = ov*tanhf(cn);
      c[b*1024 + col] = cn;
      hnew[b*1024 + col] = hv;
      hs_t[b*1024 + col] = hv;
    }
  }
}

// logits = hs @ W_out + b_out, fused per-tile logsumexp partials + gt logit capture.
// grid (63, 64), block 256. BM=32, BN=512 (2 cols/thread), BK=128.
__global__ __launch_bounds__(256,2) void logits_lse_kernel(
    const float* __restrict__ hs, const float* __restrict__ Wout,
    const float* __restrict__ bout, const int* __restrict__ gt,
    float* __restrict__ partm, float* __restrict__ parts, float* __restrict__ gtl)
{
  const int vt = blockIdx.x;   // 0..62
  const int rt = blockIdx.y;   // 0..63
  const int rowbase = rt*32;
  const int tid = threadIdx.x;
  const int vbase = vt*512;
  const int col0 = vbase + tid;
  const int col1 = col0 + 256;
  const bool v1ok = col1 < 32000;
  const int col1c = v1ok ? col1 : 31999;
  __shared__ float A[32][128];
  __shared__ float tile[32][264];
  float acc0[32], acc1[32];
#pragma unroll
  for (int r=0;r<32;++r){acc0[r]=0.f;acc1[r]=0.f;}
  for (int kb=0; kb<1024; kb+=128){
    __syncthreads();
#pragma unroll
    for (int i=0;i<16;++i){
      int idx = i*256 + tid;
      int r = idx>>7, c2 = idx&127;
      A[r][c2] = hs[(rowbase+r)*1024 + kb + c2];
    }
    __syncthreads();
#pragma unroll 2
    for (int kk=0; kk<128; kk+=4){
      float wa[4], wb[4];
#pragma unroll
      for (int j=0;j<4;++j){
        wa[j] = Wout[(kb+kk+j)*32000 + col0];
        wb[j] = Wout[(kb+kk+j)*32000 + col1c];
      }
#pragma unroll
      for (int r=0;r<32;++r){
        const float4 a = *(const float4*)&A[r][kk];
        acc0[r] += a.x*wa[0]+a.y*wa[1]+a.z*wa[2]+a.w*wa[3];
        acc1[r] += a.x*wb[0]+a.y*wb[1]+a.z*wb[2]+a.w*wb[3];
      }
    }
  }
  const float b0 = bout[col0];
  const float b1 = bout[col1c];
  const int row = tid >> 3, sub = tid & 7;
  float pm[2], psv[2];
  // ---- pass 0: cols [vbase, vbase+256)
  __syncthreads();
#pragma unroll
  for (int r=0;r<32;++r) tile[r][tid] = acc0[r] + b0;
  __syncthreads();
  {
    float m = -1e30f;
    for (int j=sub;j<256;j+=8) m = fmaxf(m, tile[row][j]);
#pragma unroll
    for (int off=4;off>=1;off>>=1) m = fmaxf(m, __shfl_xor(m, off, 8));
    float sv = 0.f;
    for (int j=sub;j<256;j+=8) sv += __expf(tile[row][j]-m);
#pragma unroll
    for (int off=4;off>=1;off>>=1) sv += __shfl_xor(sv, off, 8);
    pm[0]=m; psv[0]=sv;
  }
  if (tid<32){
    int g = gt[rowbase+tid];
    if (g>=vbase && g<vbase+256) gtl[rowbase+tid] = tile[tid][g-vbase];
  }
  // ---- pass 1: cols [vbase+256, vbase+512)
  __syncthreads();
#pragma unroll
  for (int r=0;r<32;++r) tile[r][tid] = v1ok ? (acc1[r] + b1) : -1e30f;
  __syncthreads();
  {
    float m = -1e30f;
    for (int j=sub;j<256;j+=8) m = fmaxf(m, tile[row][j]);
#pragma unroll
    for (int off=4;off>=1;off>>=1) m = fmaxf(m, __shfl_xor(m, off, 8));
    float sv = 0.f;
    for (int j=sub;j<256;j+=8) sv += __expf(tile[row][j]-m);
#pragma unroll
    for (int off=4;off>=1;off>>=1) sv += __shfl_xor(sv, off, 8);
    pm[1]=m; psv[1]=sv;
  }
  if (tid<32){
    int g = gt[rowbase+tid];
    if (g>=vbase+256 && g<vbase+512) gtl[rowbase+tid] = tile[tid][g-vbase-256];
  }
  if (sub==0){
    float m = fmaxf(pm[0], pm[1]);
    float sv = psv[0]*__expf(pm[0]-m) + psv[1]*__expf(pm[1]-m);
    partm[(rowbase+row)*NVT + vt] = m;
    parts[(rowbase+row)*NVT + vt] = sv;
  }
}

__global__ void lse_finalize(const float* __restrict__ partm, const float* __restrict__ parts,
                             const float* __restrict__ gtl, float* __restrict__ nll)
{
  int r = blockIdx.x*256 + threadIdx.x;
  if (r >= 2048) return;
  float m = -1e30f;
  for (int i=0;i<NVT;++i) m = fmaxf(m, partm[r*NVT+i]);
  float s = 0.f;
  for (int i=0;i<NVT;++i) s += parts[r*NVT+i]*__expf(partm[r*NVT+i]-m);
  nll[r] = m + logf(s) - gtl[r];
}

__global__ __launch_bounds__(256) void mean_kernel(const float* __restrict__ nll, float* __restrict__ out)
{
  __shared__ float red[4];
  int t = threadIdx.x;
  float s = 0.f;
  for (int i=t;i<2048;i+=256) s += nll[i];
#pragma unroll
  for (int off=32;off>=1;off>>=1) s += __shfl_down(s, off, 64);
  if ((t&63)==0) red[t>>6]=s;
  __syncthreads();
  if (t==0) out[0] = (red[0]+red[1]+red[2]+red[3]) * (1.0f/2048.0f);
}

extern "C" void kernel_launch(void* const* d_in, const int* in_sizes, int n_in,
                              void* d_out, int out_size, void* d_ws, size_t ws_size,
                              hipStream_t stream)
{
  const int*   tok  = (const int*)d_in[0];
  const int*   gt   = (const int*)d_in[1];
  const float* emb  = (const float*)d_in[2];
  const float* Wih  = (const float*)d_in[3];
  const float* Whh  = (const float*)d_in[4];
  const float* bias = (const float*)d_in[5];
  const float* Wout = (const float*)d_in[6];
  const float* bout = (const float*)d_in[7];
  float* out = (float*)d_out;

  float* ws    = (float*)d_ws;
  float* xproj = ws;                       // 2048*4096   = 8388608 floats
  float* hsbuf = xproj + 8388608;          // 2048*1024   = 2097152
  float* h0    = hsbuf + 2097152;          // 32*1024
  float* h1    = h0 + 32768;
  float* cbuf  = h1 + 32768;
  float* partm = cbuf + 32768;             // 2048*63
  float* parts = partm + 2048*NVT;
  float* gtl   = parts + 2048*NVT;
  float* nll   = gtl + 2048;

  // zero h0, h1, c (contiguous 98304 floats)
  zero_kernel<<<384, 256, 0, stream>>>(h0, 98304);

  xproj_kernel<<<dim3(8,64), 256, 0, stream>>>(tok, emb, Wih, bias, xproj);

  float* hb[2] = {h0, h1};
  for (int t = 0; t < 64; ++t){
    lstm_step<<<256, 256, 0, stream>>>(xproj + (size_t)t*32*4096, Whh,
        hb[t&1], hb[(t+1)&1], cbuf, hsbuf + (size_t)t*32*1024);
  }

  logits_lse_kernel<<<dim3(63,64), 256, 0, stream>>>(hsbuf, Wout, bout, gt, partm, parts, gtl);
  lse_finalize<<<8, 256, 0, stream>>>(partm, parts, gtl, nll);
  mean_kernel<<<1, 256, 0, stream>>>(nll, out);
}

// Round 3
// 746.213 us; speedup vs baseline: 7.6388x; 7.6388x over previous
//
#include <hip/hip_runtime.h>
#include <hip/hip_bf16.h>

typedef unsigned short u16;
typedef __attribute__((ext_vector_type(8))) short bf16x8;
typedef __attribute__((ext_vector_type(4))) float f32x4;

#define NSLICE 500   // 250 vocab tiles * 2 wave-columns

__device__ __forceinline__ u16 f2bf(float x){
  unsigned b = __float_as_uint(x);
  return (u16)((b + 0x7FFFu + ((b>>16)&1u)) >> 16);
}
__device__ __forceinline__ float sigm(float x){ return 1.f/(1.f+__expf(-x)); }

__device__ __forceinline__ void gload_lds16(const void* g, void* l){
  __builtin_amdgcn_global_load_lds(
      (const __attribute__((address_space(1))) unsigned int*)g,
      (__attribute__((address_space(3))) unsigned int*)l, 16, 0, 0);
}
// XOR swizzle within a 128B (64 bf16) row: spreads 16 rows over 8 bank slots.
#define SWZ(row, kb) ((kb) ^ (((row)&7)<<4))

__global__ void zero_f32(float* p, int n){
  int i = blockIdx.x*blockDim.x + threadIdx.x;
  if (i < n) p[i] = 0.f;
}

// in [K][N] f32 -> out [N][K] bf16 (K-contiguous rows for MFMA fragments)
__global__ __launch_bounds__(256) void transpose_to_bf16(
    const float* __restrict__ in, u16* __restrict__ out, int N, int K)
{
  __shared__ float tile[64][65];
  const int nb = blockIdx.x*64, kb = blockIdx.y*64;
  const int t = threadIdx.x;
#pragma unroll
  for (int i=0;i<16;++i){
    int idx = i*256 + t;
    int k = idx>>6, n = idx&63;
    tile[k][n] = in[(size_t)(kb+k)*N + nb + n];
  }
  __syncthreads();
#pragma unroll
  for (int i=0;i<16;++i){
    int idx = i*256 + t;
    int n = idx>>6, k = idx&63;
    out[(size_t)(nb+n)*K + kb + k] = f2bf(tile[k][n]);
  }
}

// embg[r][:] = bf16(embedding[tok[r]][:])   (2048 blocks x 256 thr, 4 elems/thr)
__global__ __launch_bounds__(256) void gather_emb_bf16(
    const int* __restrict__ tok, const float* __restrict__ emb, u16* __restrict__ out)
{
  const int r = blockIdx.x, t = threadIdx.x;
  const int trow = tok[r];
  const float4 v = *(const float4*)(emb + (size_t)trow*1024 + t*4);
  unsigned long long o = (unsigned long long)f2bf(v.x)
                       | ((unsigned long long)f2bf(v.y)<<16)
                       | ((unsigned long long)f2bf(v.z)<<32)
                       | ((unsigned long long)f2bf(v.w)<<48);
  *(unsigned long long*)(out + (size_t)r*1024 + t*4) = o;
}

// m97-structure 128x128 bf16 GEMM tile core. A[M][1024], BT[N][1024], both bf16
// k-contiguous. 256 thr = 4 waves (2x2). Each wave: 4x4 16x16x32 fragments.
__device__ __forceinline__ void gemm_tile_128(
    const u16* __restrict__ A, const u16* __restrict__ BT,
    int rowbase, int colbase, u16* As, u16* Bs, f32x4 (&acc)[4][4])
{
  const int tid = threadIdx.x;
  const int lane = tid & 63;
  const int wm = (tid>>6)>>1, wn = (tid>>6)&1;
#pragma unroll
  for (int m=0;m<4;++m)
#pragma unroll
    for (int n=0;n<4;++n) acc[m][n] = (f32x4){0.f,0.f,0.f,0.f};

  for (int kb = 0; kb < 1024; kb += 64){
    __syncthreads();
#pragma unroll
    for (int i=0;i<4;++i){
      const int row = i*32 + (tid>>3);
      const int kf  = (tid&7)*16;   // byte offset within 128B row
      gload_lds16((const char*)(A  + (size_t)(rowbase+row)*1024 + kb) + SWZ(row,kf),
                  (char*)As + (i*256+tid)*16);
      gload_lds16((const char*)(BT + (size_t)(colbase+row)*1024 + kb) + SWZ(row,kf),
                  (char*)Bs + (i*256+tid)*16);
    }
    __syncthreads();
#pragma unroll
    for (int ks=0;ks<2;++ks){
      bf16x8 af[4], bfr[4];
      const int kbyte = ks*64 + (lane>>4)*16;
#pragma unroll
      for (int m=0;m<4;++m){
        const int row = wm*64 + m*16 + (lane&15);
        af[m] = *(const bf16x8*)((const char*)As + row*128 + SWZ(row,kbyte));
      }
#pragma unroll
      for (int n=0;n<4;++n){
        const int col = wn*64 + n*16 + (lane&15);
        bfr[n] = *(const bf16x8*)((const char*)Bs + col*128 + SWZ(col,kbyte));
      }
#pragma unroll
      for (int m=0;m<4;++m)
#pragma unroll
        for (int n=0;n<4;++n)
          acc[m][n] = __builtin_amdgcn_mfma_f32_16x16x32_bf16(af[m], bfr[n], acc[m][n], 0,0,0);
    }
  }
}

// xproj = embg @ WihT^T + b : [2048][4096] f32 out
__global__ __launch_bounds__(256,2) void xproj_gemm(
    const u16* __restrict__ Aemb, const u16* __restrict__ WihT,
    const float* __restrict__ bias, float* __restrict__ xproj)
{
  __shared__ u16 As[8192], Bs[8192];
  const int ct = blockIdx.x, rt = blockIdx.y;
  const int rowbase = rt*128, colbase = ct*128;
  const int tid = threadIdx.x, lane = tid&63;
  const int wm = (tid>>6)>>1, wn = (tid>>6)&1;
  f32x4 acc[4][4];
  gemm_tile_128(Aemb, WihT, rowbase, colbase, As, Bs, acc);
  float bv[4];
#pragma unroll
  for (int n=0;n<4;++n) bv[n] = bias[colbase + wn*64 + n*16 + (lane&15)];
#pragma unroll
  for (int m=0;m<4;++m)
#pragma unroll
    for (int n=0;n<4;++n)
#pragma unroll
      for (int r=0;r<4;++r){
        const int row = rowbase + wm*64 + m*16 + (lane>>4)*4 + r;
        const int col = colbase + wn*64 + n*16 + (lane&15);
        xproj[(size_t)row*4096 + col] = acc[m][n][r] + bv[n];
      }
}

// One LSTM step. gates[32][4096] = h_bf @ WhhT^T (wave K-split 4x256),
// LDS reduce, fused pointwise. 256 blocks (4 hcols each) x 256 thr.
__global__ __launch_bounds__(256) void lstm_step_mfma(
    const u16* __restrict__ hin, const u16* __restrict__ WhhT,
    const float* __restrict__ xg, float* __restrict__ ccell,
    u16* __restrict__ hout, u16* __restrict__ hs_t)
{
  __shared__ float red[4*32*16];   // [wave][brow][f]
  const int cb = blockIdx.x;
  const int tid = threadIdx.x, lane = tid&63, w = tid>>6;
  const int f = lane & 15;
  const int gcol = cb*4 + (f&3) + 1024*(f>>2);
  const int kfrag = (lane>>4)*8;
  f32x4 acc0 = (f32x4){0.f,0.f,0.f,0.f};
  f32x4 acc1 = (f32x4){0.f,0.f,0.f,0.f};
  const int kb0 = w*256;
#pragma unroll
  for (int kk=0; kk<256; kk+=32){
    const int k = kb0 + kk + kfrag;
    const bf16x8 bfr = *(const bf16x8*)(WhhT + (size_t)gcol*1024 + k);
    const bf16x8 a0  = *(const bf16x8*)(hin + (size_t)(lane&15)*1024 + k);
    const bf16x8 a1  = *(const bf16x8*)(hin + (size_t)(16+(lane&15))*1024 + k);
    acc0 = __builtin_amdgcn_mfma_f32_16x16x32_bf16(a0, bfr, acc0, 0,0,0);
    acc1 = __builtin_amdgcn_mfma_f32_16x16x32_bf16(a1, bfr, acc1, 0,0,0);
  }
#pragma unroll
  for (int r=0;r<4;++r){
    red[w*512 + ((lane>>4)*4 + r)*16 + f]      = acc0[r];
    red[w*512 + (16 + (lane>>4)*4 + r)*16 + f] = acc1[r];
  }
  __syncthreads();
  if (tid < 128){
    const int bb = tid >> 2, j = tid & 3;
    const int hcol = cb*4 + j;
    float g4[4];
#pragma unroll
    for (int q=0;q<4;++q){
      const int ff = j + 4*q;
      float s = red[0*512 + bb*16 + ff] + red[1*512 + bb*16 + ff]
              + red[2*512 + bb*16 + ff] + red[3*512 + bb*16 + ff];
      g4[q] = s + xg[(size_t)bb*4096 + q*1024 + hcol];
    }
    const float iv = sigm(g4[0]), fv = sigm(g4[1]);
    const float gv = tanhf(g4[2]), ov = sigm(g4[3]);
    const int hidx = bb*1024 + hcol;
    const float cn = fv*ccell[hidx] + iv*gv;
    const float hv = ov*tanhf(cn);
    ccell[hidx] = cn;
    const u16 hb = f2bf(hv);
    hout[hidx] = hb;
    hs_t[hidx] = hb;
  }
}

// logits tile GEMM + fused per-tile logsumexp partials + gt logit capture.
__global__ __launch_bounds__(256,2) void logits_gemm_lse(
    const u16* __restrict__ hs, const u16* __restrict__ WoutT,
    const float* __restrict__ bout, const int* __restrict__ gt,
    float* __restrict__ partm, float* __restrict__ parts, float* __restrict__ gtl)
{
  __shared__ u16 As[8192], Bs[8192];
  __shared__ int gts[128];
  const int vt = blockIdx.x, rt = blockIdx.y;
  const int rowbase = rt*128, colbase = vt*128;
  const int tid = threadIdx.x, lane = tid&63;
  const int wm = (tid>>6)>>1, wn = (tid>>6)&1;
  if (tid < 128) gts[tid] = gt[rowbase + tid];
  f32x4 acc[4][4];
  gemm_tile_128(hs, WoutT, rowbase, colbase, As, Bs, acc);
  float bv[4];
#pragma unroll
  for (int n=0;n<4;++n) bv[n] = bout[colbase + wn*64 + n*16 + (lane&15)];
#pragma unroll
  for (int m=0;m<4;++m)
#pragma unroll
    for (int n=0;n<4;++n)
#pragma unroll
      for (int r=0;r<4;++r) acc[m][n][r] += bv[n];
  // per-row (16 cols per frag x 4 n-frags = wave's 64 cols) max & sumexp
  float rm[4][4], rs[4][4];
#pragma unroll
  for (int m=0;m<4;++m)
#pragma unroll
    for (int r=0;r<4;++r){
      float mx = fmaxf(fmaxf(acc[m][0][r],acc[m][1][r]), fmaxf(acc[m][2][r],acc[m][3][r]));
      mx = fmaxf(mx, __shfl_xor(mx,1,16));
      mx = fmaxf(mx, __shfl_xor(mx,2,16));
      mx = fmaxf(mx, __shfl_xor(mx,4,16));
      mx = fmaxf(mx, __shfl_xor(mx,8,16));
      float sv = __expf(acc[m][0][r]-mx) + __expf(acc[m][1][r]-mx)
               + __expf(acc[m][2][r]-mx) + __expf(acc[m][3][r]-mx);
      sv += __shfl_xor(sv,1,16);
      sv += __shfl_xor(sv,2,16);
      sv += __shfl_xor(sv,4,16);
      sv += __shfl_xor(sv,8,16);
      rm[m][r]=mx; rs[m][r]=sv;
    }
  const int slice = vt*2 + wn;
  if ((lane&15)==0){
#pragma unroll
    for (int m=0;m<4;++m)
#pragma unroll
      for (int r=0;r<4;++r){
        const int rloc = wm*64 + m*16 + (lane>>4)*4 + r;
        partm[(size_t)slice*2048 + rowbase + rloc] = rm[m][r];
        parts[(size_t)slice*2048 + rowbase + rloc] = rs[m][r];
      }
  }
#pragma unroll
  for (int m=0;m<4;++m)
#pragma unroll
    for (int r=0;r<4;++r){
      const int rloc = wm*64 + m*16 + (lane>>4)*4 + r;
      const int g = gts[rloc] - colbase - wn*64;
      if (g >= 0 && g < 64 && (g&15)==(lane&15)){
        const int n = g>>4;
        const float val = (n==0)?acc[m][0][r] : (n==1)?acc[m][1][r]
                        : (n==2)?acc[m][2][r] : acc[m][3][r];
        gtl[rowbase+rloc] = val;
      }
    }
}

__global__ __launch_bounds__(256) void lse_finalize2(
    const float* __restrict__ partm, const float* __restrict__ parts,
    const float* __restrict__ gtl, float* __restrict__ nll)
{
  const int r = blockIdx.x*256 + threadIdx.x;
  if (r >= 2048) return;
  float m = -1e30f;
  for (int i=0;i<NSLICE;++i) m = fmaxf(m, partm[(size_t)i*2048 + r]);
  float s = 0.f;
  for (int i=0;i<NSLICE;++i) s += parts[(size_t)i*2048 + r]*__expf(partm[(size_t)i*2048 + r]-m);
  nll[r] = m + logf(s) - gtl[r];
}

__global__ __launch_bounds__(256) void mean_kernel(const float* __restrict__ nll, float* __restrict__ out)
{
  __shared__ float red[4];
  const int t = threadIdx.x;
  float s = 0.f;
  for (int i=t;i<2048;i+=256) s += nll[i];
#pragma unroll
  for (int off=32;off>=1;off>>=1) s += __shfl_down(s, off, 64);
  if ((t&63)==0) red[t>>6]=s;
  __syncthreads();
  if (t==0) out[0] = (red[0]+red[1]+red[2]+red[3]) * (1.0f/2048.0f);
}

extern "C" void kernel_launch(void* const* d_in, const int* in_sizes, int n_in,
                              void* d_out, int out_size, void* d_ws, size_t ws_size,
                              hipStream_t stream)
{
  const int*   tok  = (const int*)d_in[0];
  const int*   gt   = (const int*)d_in[1];
  const float* emb  = (const float*)d_in[2];
  const float* Wih  = (const float*)d_in[3];
  const float* Whh  = (const float*)d_in[4];
  const float* bias = (const float*)d_in[5];
  const float* Wout = (const float*)d_in[6];
  const float* bout = (const float*)d_in[7];
  float* out = (float*)d_out;

  char* base = (char*)d_ws;
  u16*   WoutT = (u16*)base;            base += 65536000;   // 32000*1024*2
  u16*   WihT  = (u16*)base;            base += 8388608;    // 4096*1024*2
  u16*   WhhT  = (u16*)base;            base += 8388608;
  u16*   embg  = (u16*)base;            base += 4194304;    // 2048*1024*2
  float* xproj = (float*)base;          base += 33554432;   // 2048*4096*4
  u16*   hsbf  = (u16*)base;            base += 4194304;    // 2048*1024*2
  float* cbuf  = (float*)base;          base += 131072;     // 32*1024*4
  u16*   hb0   = (u16*)base;            base += 65536;      // 32*1024*2
  u16*   hb1   = (u16*)base;            base += 65536;
  float* partm = (float*)base;          base += 4096000;    // 500*2048*4
  float* parts = (float*)base;          base += 4096000;
  float* gtl   = (float*)base;          base += 8192;
  float* nll   = (float*)base;          base += 8192;

  // zero c + both h buffers (contiguous 262144 B = 65536 f32)
  zero_f32<<<256, 256, 0, stream>>>(cbuf, 65536);

  transpose_to_bf16<<<dim3(64,16),  256, 0, stream>>>(Wih,  WihT,  4096,  1024);
  transpose_to_bf16<<<dim3(64,16),  256, 0, stream>>>(Whh,  WhhT,  4096,  1024);
  transpose_to_bf16<<<dim3(500,16), 256, 0, stream>>>(Wout, WoutT, 32000, 1024);
  gather_emb_bf16<<<2048, 256, 0, stream>>>(tok, emb, embg);

  xproj_gemm<<<dim3(32,16), 256, 0, stream>>>(embg, WihT, bias, xproj);

  for (int t = 0; t < 64; ++t){
    const u16* hin = (t & 1) ? hb1 : hb0;
    u16*      hout = (t & 1) ? hb0 : hb1;
    lstm_step_mfma<<<256, 256, 0, stream>>>(hin, WhhT,
        xproj + (size_t)t*131072, cbuf, hout, hsbf + (size_t)t*32768);
  }

  logits_gemm_lse<<<dim3(250,16), 256, 0, stream>>>(hsbf, WoutT, bout, gt, partm, parts, gtl);
  lse_finalize2<<<8, 256, 0, stream>>>(partm, parts, gtl, nll);
  mean_kernel<<<1, 256, 0, stream>>>(nll, out);
}